// Round 1
// baseline (736.816 us; speedup 1.0000x reference)
//
#include <hip/hip_runtime.h>
#include <hip/hip_bf16.h>

typedef unsigned short ushort_t;
typedef float f32x4 __attribute__((ext_vector_type(4)));
typedef __bf16 bf16x8 __attribute__((ext_vector_type(8)));

#define BM 128
#define BN 128
#define BK 32

// round-to-nearest-even fp32 -> bf16 (finite inputs only)
__device__ __forceinline__ unsigned short f2bf(float f) {
    unsigned int u = __float_as_uint(f);
    unsigned int lsb = (u >> 16) & 1u;
    u += 0x7fffu + lsb;
    return (unsigned short)(u >> 16);
}

__device__ __forceinline__ void load_lds16(const unsigned short* g, unsigned short* l) {
    __builtin_amdgcn_global_load_lds((const __attribute__((address_space(1))) void*)g,
                                     (__attribute__((address_space(3))) void*)l,
                                     16, 0, 0);
}

// ---------------- conversion kernels ----------------
__global__ void cvt_f32_to_bf16_k(const float* __restrict__ in,
                                  unsigned short* __restrict__ out, int n) {
    int stride = gridDim.x * blockDim.x;
    for (int i = blockIdx.x * blockDim.x + threadIdx.x; i * 4 < n; i += stride) {
        float4 v = *reinterpret_cast<const float4*>(in + (size_t)i * 4);
        ushort4 o = make_ushort4(f2bf(v.x), f2bf(v.y), f2bf(v.z), f2bf(v.w));
        *reinterpret_cast<ushort4*>(out + (size_t)i * 4) = o;
    }
}

__global__ void cvt_i32_to_bf16_k(const int* __restrict__ in,
                                  unsigned short* __restrict__ out, int n,
                                  const int* __restrict__ zp) {
    int z = zp[0];
    int stride = gridDim.x * blockDim.x;
    for (int i = blockIdx.x * blockDim.x + threadIdx.x; i * 4 < n; i += stride) {
        int4 v = *reinterpret_cast<const int4*>(in + (size_t)i * 4);
        // |q - z| <= 254: exact in bf16
        ushort4 o = make_ushort4(f2bf((float)(v.x - z)), f2bf((float)(v.y - z)),
                                 f2bf((float)(v.z - z)), f2bf((float)(v.w - z)));
        *reinterpret_cast<ushort4*>(out + (size_t)i * 4) = o;
    }
}

// ---------------- GEMM: C[M,N] = A[M,K] * Bt[N,K]^T ----------------
// EPI 0: v = acc*s_w + s_b*(bias_q[n]-z_b); out = bf16(gelu_exact(v)) -> ushort C
// EPI 1: v = acc*s_w + s_b*(bias_q[n]-z_b); out = float v             -> float C
template <int EPI>
__global__ __launch_bounds__(256, 2) void gemm_bt(
    const unsigned short* __restrict__ A,
    const unsigned short* __restrict__ Bt,
    void* __restrict__ Cout,
    const int* __restrict__ bias_q,
    const float* __restrict__ s_w_p,
    const float* __restrict__ s_b_p,
    const int* __restrict__ z_b_p,
    int M, int N, int K)
{
    __shared__ __align__(16) unsigned short ldsA[2][BM * BK];
    __shared__ __align__(16) unsigned short ldsB[2][BN * BK];

    const int tid  = threadIdx.x;
    const int wave = tid >> 6;
    const int lane = tid & 63;
    const int wr = wave >> 1, wc = wave & 1;

    const int brow = blockIdx.y * BM;
    const int bcol = blockIdx.x * BN;

    f32x4 acc[4][4] = {};

    const int KT = K / BK;

    auto stage = [&](int buf, int kt) {
#pragma unroll
        for (int it = 0; it < 2; ++it) {
            int chunk = it * 256 + tid;
            int elem  = chunk * 8;
            int row = elem >> 5;      // /BK
            int col = elem & (BK - 1);
            const unsigned short* g = A + (size_t)(brow + row) * K + kt * BK + col;
            unsigned short* l = &ldsA[buf][(it * 256 + wave * 64) * 8];
            load_lds16(g, l);
        }
#pragma unroll
        for (int it = 0; it < 2; ++it) {
            int chunk = it * 256 + tid;
            int elem  = chunk * 8;
            int row = elem >> 5;
            int col = elem & (BK - 1);
            const unsigned short* g = Bt + (size_t)(bcol + row) * K + kt * BK + col;
            unsigned short* l = &ldsB[buf][(it * 256 + wave * 64) * 8];
            load_lds16(g, l);
        }
    };

    auto compute = [&](int buf) {
        const int ko  = (lane >> 4) * 8;   // k-chunk within BK
        const int r15 = lane & 15;
        bf16x8 a[4], b[4];
#pragma unroll
        for (int m = 0; m < 4; ++m) {
            int row = wr * 64 + m * 16 + r15;
            a[m] = *reinterpret_cast<const bf16x8*>(&ldsA[buf][row * BK + ko]);
        }
#pragma unroll
        for (int n = 0; n < 4; ++n) {
            int row = wc * 64 + n * 16 + r15;
            b[n] = *reinterpret_cast<const bf16x8*>(&ldsB[buf][row * BK + ko]);
        }
#pragma unroll
        for (int m = 0; m < 4; ++m)
#pragma unroll
            for (int n = 0; n < 4; ++n)
                acc[m][n] = __builtin_amdgcn_mfma_f32_16x16x32_bf16(a[m], b[n], acc[m][n], 0, 0, 0);
    };

    stage(0, 0);
    __syncthreads();
    for (int kt = 0; kt < KT; ++kt) {
        int cur = kt & 1;
        if (kt + 1 < KT) stage(cur ^ 1, kt + 1);
        compute(cur);
        __syncthreads();
    }

    // epilogue
    const float s_w = s_w_p[0];
    const float s_b = s_b_p[0];
    const int   z_b = z_b_p[0];
    const int col0 = bcol + wc * 64;
    const int row0 = brow + wr * 64;
#pragma unroll
    for (int n = 0; n < 4; ++n) {
        int col = col0 + n * 16 + (lane & 15);
        float bias = s_b * (float)(bias_q[col] - z_b);
#pragma unroll
        for (int m = 0; m < 4; ++m) {
#pragma unroll
            for (int r = 0; r < 4; ++r) {
                int row = row0 + m * 16 + (lane >> 4) * 4 + r;
                float v = acc[m][n][r] * s_w + bias;
                if (EPI == 0) {
                    float g = 0.5f * v * (1.0f + erff(v * 0.70710678118654752f));
                    ((unsigned short*)Cout)[(size_t)row * N + col] = f2bf(g);
                } else {
                    ((float*)Cout)[(size_t)row * N + col] = v;
                }
            }
        }
    }
}

extern "C" void kernel_launch(void* const* d_in, const int* in_sizes, int n_in,
                              void* d_out, int out_size, void* d_ws, size_t ws_size,
                              hipStream_t stream) {
    const float* x        = (const float*)d_in[0];
    const int*   w_fc_q   = (const int*)d_in[1];
    const int*   b_fc_q   = (const int*)d_in[2];
    const int*   w_proj_q = (const int*)d_in[3];
    const int*   b_proj_q = (const int*)d_in[4];
    const float* s_fc_w   = (const float*)d_in[5];
    const float* s_fc_b   = (const float*)d_in[6];
    const float* s_proj_w = (const float*)d_in[7];
    const float* s_proj_b = (const float*)d_in[8];
    const int*   z_fc_w   = (const int*)d_in[9];
    const int*   z_fc_b   = (const int*)d_in[10];
    const int*   z_proj_w = (const int*)d_in[11];
    const int*   z_proj_b = (const int*)d_in[12];

    const int M = 4 * 2048;   // B*S tokens
    const int E = 2048;
    const int H = 4 * 2048;

    // workspace layout (all bf16 stored as ushort)
    size_t need = ((size_t)M * E + (size_t)H * E + (size_t)E * H + (size_t)M * H) * 2;
    if (ws_size < need) return;  // fail gracefully rather than corrupt memory

    unsigned short* xb    = (unsigned short*)d_ws;
    unsigned short* wfc   = xb + (size_t)M * E;
    unsigned short* wproj = wfc + (size_t)H * E;
    unsigned short* hb    = wproj + (size_t)E * H;

    cvt_f32_to_bf16_k<<<2048, 256, 0, stream>>>(x, xb, M * E);
    cvt_i32_to_bf16_k<<<2048, 256, 0, stream>>>(w_fc_q, wfc, H * E, z_fc_w);
    cvt_i32_to_bf16_k<<<2048, 256, 0, stream>>>(w_proj_q, wproj, E * H, z_proj_w);

    // GEMM1: h[M,H] = xb[M,E] * wfc[H,E]^T ; fused scale+bias+GELU -> bf16
    dim3 g1(H / BN, M / BM);
    gemm_bt<0><<<g1, 256, 0, stream>>>(xb, wfc, hb, b_fc_q, s_fc_w, s_fc_b, z_fc_b, M, H, E);

    // GEMM2: out[M,E] = hb[M,H] * wproj[E,H]^T ; fused scale+bias -> f32
    dim3 g2(E / BN, M / BM);
    gemm_bt<1><<<g2, 256, 0, stream>>>(hb, wproj, (float*)d_out, b_proj_q,
                                       s_proj_w, s_proj_b, z_proj_b, M, E, H);
}

// Round 3
// 616.595 us; speedup vs baseline: 1.1950x; 1.1950x over previous
//
#include <hip/hip_runtime.h>
#include <hip/hip_bf16.h>

typedef float f32x4 __attribute__((ext_vector_type(4)));
typedef __bf16 bf16x8 __attribute__((ext_vector_type(8)));

#define BM 256
#define BN 256
#define KS 32        // slab K-width
#define SLABA 16384  // bytes per A slab (256 rows x 32 k x 2B)
#define SLABB 16384

// round-to-nearest-even fp32 -> bf16 (finite inputs only)
__device__ __forceinline__ unsigned short f2bf(float f) {
    unsigned int u = __float_as_uint(f);
    u += 0x7fffu + ((u >> 16) & 1u);
    return (unsigned short)(u >> 16);
}

__device__ __forceinline__ void load_lds16(const unsigned short* g, void* l) {
    __builtin_amdgcn_global_load_lds((const __attribute__((address_space(1))) void*)g,
                                     (__attribute__((address_space(3))) void*)l,
                                     16, 0, 0);
}

// ---------------- conversion kernels ----------------
__global__ void cvt_f32_to_bf16_k(const float* __restrict__ in,
                                  unsigned short* __restrict__ out, int n) {
    int stride = gridDim.x * blockDim.x;
    for (int i = blockIdx.x * blockDim.x + threadIdx.x; i * 4 < n; i += stride) {
        float4 v = *reinterpret_cast<const float4*>(in + (size_t)i * 4);
        ushort4 o = make_ushort4(f2bf(v.x), f2bf(v.y), f2bf(v.z), f2bf(v.w));
        *reinterpret_cast<ushort4*>(out + (size_t)i * 4) = o;
    }
}

__global__ void cvt_i32_to_bf16_k(const int* __restrict__ in,
                                  unsigned short* __restrict__ out, int n,
                                  const int* __restrict__ zp) {
    int z = zp[0];
    int stride = gridDim.x * blockDim.x;
    for (int i = blockIdx.x * blockDim.x + threadIdx.x; i * 4 < n; i += stride) {
        int4 v = *reinterpret_cast<const int4*>(in + (size_t)i * 4);
        ushort4 o = make_ushort4(f2bf((float)(v.x - z)), f2bf((float)(v.y - z)),
                                 f2bf((float)(v.z - z)), f2bf((float)(v.w - z)));
        *reinterpret_cast<ushort4*>(out + (size_t)i * 4) = o;
    }
}

// ---------------- 256x256 deep-pipelined GEMM: C[M,N] = A[M,K] * Bt[N,K]^T ----
// LDS slab layout (per 32-k slab, 16 KB): pair-packed [128][128B]:
//   linear chunk (rp, j) j=0..7 holds global (row 2*rp + (j>>2), k8 = j&3)
//   physical chunk index = rp*8 + (j ^ (rp&7))   (3-bit XOR swizzle)
// global_load_lds writes linearly; the XOR is applied to the GLOBAL source
// (self-inverse) and to the ds_read address (both-sides-or-neither rule).
//
// K-loop: ring of 4 slabs, 3 slabs prefetched ahead (12 loads in flight/thread),
// counted vmcnt(8) in steady state, tail peeled with vmcnt(4) / vmcnt(0)
// (the round-2 bug: vmcnt(8) is a no-op once nothing is staged past the end).

#define KSTEP(SS, VMSTR, DO_STAGE)                                             \
  {                                                                            \
    asm volatile("s_waitcnt " VMSTR ::: "memory");                             \
    __builtin_amdgcn_s_barrier();                                              \
    const int s_ = (SS);                                                       \
    const char* As = smem + (s_ & 3) * SLABA;                                  \
    const char* Bs = smem + 65536 + (s_ & 3) * SLABB;                          \
    bf16x8 a[4], b[4];                                                         \
    _Pragma("unroll") for (int m = 0; m < 4; ++m) {                            \
      int g = wr * 128 + m * 16 + l15;                                         \
      int rp = g >> 1;                                                         \
      int inner = ((g & 1) << 6) | kb;                                         \
      int off = rp * 128 + ((((inner >> 4) ^ rp) & 7) << 4);                   \
      a[m] = *reinterpret_cast<const bf16x8*>(As + off);                       \
    }                                                                          \
    _Pragma("unroll") for (int n = 0; n < 4; ++n) {                            \
      int g = wc * 64 + n * 16 + l15;                                          \
      int rp = g >> 1;                                                         \
      int inner = ((g & 1) << 6) | kb;                                         \
      int off = rp * 128 + ((((inner >> 4) ^ rp) & 7) << 4);                   \
      b[n] = *reinterpret_cast<const bf16x8*>(Bs + off);                       \
    }                                                                          \
    if (DO_STAGE) stageA(s_ + 3);                                              \
    __builtin_amdgcn_s_barrier();                                              \
    __builtin_amdgcn_s_setprio(1);                                             \
    _Pragma("unroll") for (int m = 0; m < 4; ++m)                              \
      _Pragma("unroll") for (int n = 0; n < 4; ++n)                            \
        acc[m][n] = __builtin_amdgcn_mfma_f32_16x16x32_bf16(a[m], b[n],        \
                                                            acc[m][n], 0, 0, 0); \
    __builtin_amdgcn_s_setprio(0);                                             \
    __builtin_amdgcn_s_barrier();                                              \
    _Pragma("unroll") for (int m = 0; m < 4; ++m) {                            \
      int g = wr * 128 + (m + 4) * 16 + l15;                                   \
      int rp = g >> 1;                                                         \
      int inner = ((g & 1) << 6) | kb;                                         \
      int off = rp * 128 + ((((inner >> 4) ^ rp) & 7) << 4);                   \
      a[m] = *reinterpret_cast<const bf16x8*>(As + off);                       \
    }                                                                          \
    if (DO_STAGE) stageB(s_ + 3);                                              \
    __builtin_amdgcn_s_barrier();                                              \
    __builtin_amdgcn_s_setprio(1);                                             \
    _Pragma("unroll") for (int m = 0; m < 4; ++m)                              \
      _Pragma("unroll") for (int n = 0; n < 4; ++n)                            \
        acc[m + 4][n] = __builtin_amdgcn_mfma_f32_16x16x32_bf16(a[m], b[n],    \
                                                         acc[m + 4][n], 0, 0, 0); \
    __builtin_amdgcn_s_setprio(0);                                             \
  }

template <int EPI>
__global__ __launch_bounds__(512, 2) void gemm8(
    const unsigned short* __restrict__ A,
    const unsigned short* __restrict__ Bt,
    void* __restrict__ Cout,
    const int* __restrict__ bias_q,
    const float* __restrict__ s_w_p,
    const float* __restrict__ s_b_p,
    const int* __restrict__ z_b_p,
    int M, int N, int K)
{
    extern __shared__ char smem[];   // 131072 B: A ring [0,64K), B ring [64K,128K)

    const int tid  = threadIdx.x;
    const int wave = tid >> 6;
    const int lane = tid & 63;
    const int wr = wave >> 2;        // 0..1 : row half
    const int wc = wave & 3;         // 0..3 : col quarter

    // XCD-aware bijective swizzle (gridDim.x % 8 == 0 for both GEMMs)
    const int nwg = gridDim.x;
    const int cpx = nwg >> 3;
    const int swz = (blockIdx.x & 7) * cpx + (blockIdx.x >> 3);
    const int nbx = N / BN;
    const int brow = (swz / nbx) * BM;
    const int bcol = (swz % nbx) * BN;

    const int NSLAB = K / KS;

    auto stageA = [&](int s) {
        char* base = smem + (s & 3) * SLABA;
#pragma unroll
        for (int h = 0; h < 2; ++h) {
            int p  = h * 512 + tid;
            int rp = p >> 3;
            int j  = (p & 7) ^ (rp & 7);
            const unsigned short* src =
                A + (size_t)(brow + 2 * rp + (j >> 2)) * K + s * KS + (j & 3) * 8;
            void* dst = base + (h * 512 + wave * 64) * 16;  // wave-uniform; HW adds lane*16
            load_lds16(src, dst);
        }
    };
    auto stageB = [&](int s) {
        char* base = smem + 65536 + (s & 3) * SLABB;
#pragma unroll
        for (int h = 0; h < 2; ++h) {
            int p  = h * 512 + tid;
            int rp = p >> 3;
            int j  = (p & 7) ^ (rp & 7);
            const unsigned short* src =
                Bt + (size_t)(bcol + 2 * rp + (j >> 2)) * K + s * KS + (j & 3) * 8;
            void* dst = base + (h * 512 + wave * 64) * 16;
            load_lds16(src, dst);
        }
    };

    f32x4 acc[8][4] = {};

    // prologue: stage slabs 0,1,2 (12 loads/thread in flight)
    stageA(0); stageB(0);
    stageA(1); stageB(1);
    stageA(2); stageB(2);

    const int kb  = (lane >> 4) * 16;  // byte offset of this lane's k-chunk
    const int l15 = lane & 15;

    // steady state: at loop top, slabs s,s+1,s+2 outstanding (12 loads);
    // vmcnt(8) completes slab s's 4.
    for (int s = 0; s < NSLAB - 2; ++s) {
        KSTEP(s, "vmcnt(8)", (s + 3 < NSLAB));
    }
    // tail: 8 then 4 loads outstanding — drain 4 -> 0.
    KSTEP(NSLAB - 2, "vmcnt(4)", false);
    KSTEP(NSLAB - 1, "vmcnt(0)", false);

    // ---------------- epilogue ----------------
    const float s_w = s_w_p[0];
    const float s_b = s_b_p[0];
    const int   z_b = z_b_p[0];
    const int row0 = brow + wr * 128;
    const int col0 = bcol + wc * 64;
#pragma unroll
    for (int n = 0; n < 4; ++n) {
        int col = col0 + n * 16 + l15;
        float bias = s_b * (float)(bias_q[col] - z_b);
#pragma unroll
        for (int m = 0; m < 8; ++m) {
#pragma unroll
            for (int r = 0; r < 4; ++r) {
                int row = row0 + m * 16 + (lane >> 4) * 4 + r;
                float v = acc[m][n][r] * s_w + bias;
                if (EPI == 0) {
                    float ge = 0.5f * v * (1.0f + erff(v * 0.70710678118654752f));
                    ((unsigned short*)Cout)[(size_t)row * N + col] = f2bf(ge);
                } else {
                    ((float*)Cout)[(size_t)row * N + col] = v;
                }
            }
        }
    }
}

extern "C" void kernel_launch(void* const* d_in, const int* in_sizes, int n_in,
                              void* d_out, int out_size, void* d_ws, size_t ws_size,
                              hipStream_t stream) {
    const float* x        = (const float*)d_in[0];
    const int*   w_fc_q   = (const int*)d_in[1];
    const int*   b_fc_q   = (const int*)d_in[2];
    const int*   w_proj_q = (const int*)d_in[3];
    const int*   b_proj_q = (const int*)d_in[4];
    const float* s_fc_w   = (const float*)d_in[5];
    const float* s_fc_b   = (const float*)d_in[6];
    const float* s_proj_w = (const float*)d_in[7];
    const float* s_proj_b = (const float*)d_in[8];
    const int*   z_fc_w   = (const int*)d_in[9];
    const int*   z_fc_b   = (const int*)d_in[10];
    const int*   z_proj_w = (const int*)d_in[11];
    const int*   z_proj_b = (const int*)d_in[12];

    const int M = 4 * 2048;
    const int E = 2048;
    const int H = 4 * 2048;

    size_t need = ((size_t)M * E + (size_t)H * E + (size_t)E * H + (size_t)M * H) * 2;
    if (ws_size < need) return;

    unsigned short* xb    = (unsigned short*)d_ws;
    unsigned short* wfc   = xb + (size_t)M * E;
    unsigned short* wproj = wfc + (size_t)H * E;
    unsigned short* hb    = wproj + (size_t)E * H;

    // allow 128 KiB dynamic LDS (idempotent host-side call; graph-capture safe)
    hipFuncSetAttribute(reinterpret_cast<const void*>(gemm8<0>),
                        hipFuncAttributeMaxDynamicSharedMemorySize, 131072);
    hipFuncSetAttribute(reinterpret_cast<const void*>(gemm8<1>),
                        hipFuncAttributeMaxDynamicSharedMemorySize, 131072);

    cvt_f32_to_bf16_k<<<2048, 256, 0, stream>>>(x, xb, M * E);
    cvt_i32_to_bf16_k<<<2048, 256, 0, stream>>>(w_fc_q, wfc, H * E, z_fc_w);
    cvt_i32_to_bf16_k<<<2048, 256, 0, stream>>>(w_proj_q, wproj, E * H, z_proj_w);

    // GEMM1: h[M,H] = xb * wfc^T ; scale+bias+exact GELU -> bf16
    gemm8<0><<<dim3((M / BM) * (H / BN)), 512, 131072, stream>>>(
        xb, wfc, hb, b_fc_q, s_fc_w, s_fc_b, z_fc_b, M, H, E);

    // GEMM2: out[M,E] = hb * wproj^T ; scale+bias -> f32
    gemm8<1><<<dim3((M / BM) * (E / BN)), 512, 131072, stream>>>(
        hb, wproj, (float*)d_out, b_proj_q, s_proj_w, s_proj_b, z_proj_b, M, E, H);
}

// Round 4
// 587.941 us; speedup vs baseline: 1.2532x; 1.0487x over previous
//
#include <hip/hip_runtime.h>
#include <hip/hip_bf16.h>

typedef float f32x4 __attribute__((ext_vector_type(4)));
typedef __bf16 bf16x8 __attribute__((ext_vector_type(8)));

#define BM 256
#define BN 256
#define KS 32        // slab K-width
#define SLABA 16384  // bytes per A slab (256 rows x 32 k x 2B)
#define SLABB 16384

// round-to-nearest-even fp32 -> bf16 (finite inputs only)
__device__ __forceinline__ unsigned short f2bf(float f) {
    unsigned int u = __float_as_uint(f);
    u += 0x7fffu + ((u >> 16) & 1u);
    return (unsigned short)(u >> 16);
}

__device__ __forceinline__ void load_lds16(const unsigned short* g, void* l) {
    __builtin_amdgcn_global_load_lds((const __attribute__((address_space(1))) void*)g,
                                     (__attribute__((address_space(3))) void*)l,
                                     16, 0, 0);
}

// ---------------- conversion kernels ----------------
__global__ void cvt_f32_to_bf16_k(const float* __restrict__ in,
                                  unsigned short* __restrict__ out, int n) {
    int stride = gridDim.x * blockDim.x;
    for (int i = blockIdx.x * blockDim.x + threadIdx.x; i * 4 < n; i += stride) {
        float4 v = *reinterpret_cast<const float4*>(in + (size_t)i * 4);
        ushort4 o = make_ushort4(f2bf(v.x), f2bf(v.y), f2bf(v.z), f2bf(v.w));
        *reinterpret_cast<ushort4*>(out + (size_t)i * 4) = o;
    }
}

__global__ void cvt_i32_to_bf16_k(const int* __restrict__ in,
                                  unsigned short* __restrict__ out, int n,
                                  const int* __restrict__ zp) {
    int z = zp[0];
    int stride = gridDim.x * blockDim.x;
    for (int i = blockIdx.x * blockDim.x + threadIdx.x; i * 4 < n; i += stride) {
        int4 v = *reinterpret_cast<const int4*>(in + (size_t)i * 4);
        ushort4 o = make_ushort4(f2bf((float)(v.x - z)), f2bf((float)(v.y - z)),
                                 f2bf((float)(v.z - z)), f2bf((float)(v.w - z)));
        *reinterpret_cast<ushort4*>(out + (size_t)i * 4) = o;
    }
}

// ---------------- 256x256 deep-pipelined GEMM: C[M,N] = A[M,K] * Bt[N,K]^T ----
// LDS slab layout (per 32-k slab, 16 KB): pair-packed [128][128B]:
//   linear chunk (rp, j) j=0..7 holds global (row 2*rp + (j>>2), k8 = j&3)
//   physical chunk index = rp*8 + (j ^ (rp&7))   (3-bit XOR swizzle)
// global_load_lds writes linearly; the XOR is applied to the GLOBAL source
// (self-inverse) and to the ds_read address (both-sides-or-neither rule).
//
// K-loop: ring of 4 slabs, 3 slabs prefetched ahead (12 loads in flight/thread),
// counted vmcnt(8) in steady state, tail peeled with vmcnt(4) / vmcnt(0).
//
// Block map (round-4 change): the ~256 concurrently-resident blocks must share
// staging panels WITHIN each XCD's private L2 (the 256^2 tile needs ~16 TB/s of
// staging; only L2 can feed that). Map gives each XCD a 4-row x 8-col rectangle
// per round; rounds advance along columns. Per-XCD per-slab sliding window =
// (4 A + 8 B) x 16KB = 192 KB -> L2-resident.

#define KSTEP(SS, VMSTR, DO_STAGE)                                             \
  {                                                                            \
    asm volatile("s_waitcnt " VMSTR ::: "memory");                             \
    __builtin_amdgcn_s_barrier();                                              \
    const int s_ = (SS);                                                       \
    const char* As = smem + (s_ & 3) * SLABA;                                  \
    const char* Bs = smem + 65536 + (s_ & 3) * SLABB;                          \
    bf16x8 a[4], b[4];                                                         \
    _Pragma("unroll") for (int m = 0; m < 4; ++m) {                            \
      int g = wr * 128 + m * 16 + l15;                                         \
      int rp = g >> 1;                                                         \
      int inner = ((g & 1) << 6) | kb;                                         \
      int off = rp * 128 + ((((inner >> 4) ^ rp) & 7) << 4);                   \
      a[m] = *reinterpret_cast<const bf16x8*>(As + off);                       \
    }                                                                          \
    _Pragma("unroll") for (int n = 0; n < 4; ++n) {                            \
      int g = wc * 64 + n * 16 + l15;                                          \
      int rp = g >> 1;                                                         \
      int inner = ((g & 1) << 6) | kb;                                         \
      int off = rp * 128 + ((((inner >> 4) ^ rp) & 7) << 4);                   \
      b[n] = *reinterpret_cast<const bf16x8*>(Bs + off);                       \
    }                                                                          \
    if (DO_STAGE) stageA(s_ + 3);                                              \
    __builtin_amdgcn_s_barrier();                                              \
    __builtin_amdgcn_s_setprio(1);                                             \
    _Pragma("unroll") for (int m = 0; m < 4; ++m)                              \
      _Pragma("unroll") for (int n = 0; n < 4; ++n)                            \
        acc[m][n] = __builtin_amdgcn_mfma_f32_16x16x32_bf16(a[m], b[n],        \
                                                            acc[m][n], 0, 0, 0); \
    __builtin_amdgcn_s_setprio(0);                                             \
    __builtin_amdgcn_s_barrier();                                              \
    _Pragma("unroll") for (int m = 0; m < 4; ++m) {                            \
      int g = wr * 128 + (m + 4) * 16 + l15;                                   \
      int rp = g >> 1;                                                         \
      int inner = ((g & 1) << 6) | kb;                                         \
      int off = rp * 128 + ((((inner >> 4) ^ rp) & 7) << 4);                   \
      a[m] = *reinterpret_cast<const bf16x8*>(As + off);                       \
    }                                                                          \
    if (DO_STAGE) stageB(s_ + 3);                                              \
    __builtin_amdgcn_s_barrier();                                              \
    __builtin_amdgcn_s_setprio(1);                                             \
    _Pragma("unroll") for (int m = 0; m < 4; ++m)                              \
      _Pragma("unroll") for (int n = 0; n < 4; ++n)                            \
        acc[m + 4][n] = __builtin_amdgcn_mfma_f32_16x16x32_bf16(a[m], b[n],    \
                                                         acc[m + 4][n], 0, 0, 0); \
    __builtin_amdgcn_s_setprio(0);                                             \
  }

template <int EPI>
__global__ __launch_bounds__(512, 2) void gemm8(
    const unsigned short* __restrict__ A,
    const unsigned short* __restrict__ Bt,
    void* __restrict__ Cout,
    const int* __restrict__ bias_q,
    const float* __restrict__ s_w_p,
    const float* __restrict__ s_b_p,
    const int* __restrict__ z_b_p,
    int M, int N, int K)
{
    extern __shared__ char smem[];   // 131072 B: A ring [0,64K), B ring [64K,128K)

    const int tid  = threadIdx.x;
    const int wave = tid >> 6;
    const int lane = tid & 63;
    const int wr = wave >> 2;        // 0..1 : row half
    const int wc = wave & 3;         // 0..3 : col quarter

    // Block map: 32 row-panels fixed (M=8192). Each round = 256 blocks covering
    // all 32 rows x 8 cols; XCD x owns rows 4x..4x+3 of that rectangle.
    // Requires: gridDim.x % 256 == 0, N/BN % 8 == 0. Bijective.
    const int bid  = blockIdx.x;
    const int x8   = bid & 7;          // XCD
    const int j32  = (bid >> 3) & 31;  // block within XCD-round
    const int rnd  = bid >> 8;         // column-octet round
    const int brow = (4 * x8 + (j32 >> 3)) * BM;
    const int bcol = (rnd * 8 + (j32 & 7)) * BN;

    const int NSLAB = K / KS;

    auto stageA = [&](int s) {
        char* base = smem + (s & 3) * SLABA;
#pragma unroll
        for (int h = 0; h < 2; ++h) {
            int p  = h * 512 + tid;
            int rp = p >> 3;
            int j  = (p & 7) ^ (rp & 7);
            const unsigned short* src =
                A + (size_t)(brow + 2 * rp + (j >> 2)) * K + s * KS + (j & 3) * 8;
            void* dst = base + (h * 512 + wave * 64) * 16;  // wave-uniform; HW adds lane*16
            load_lds16(src, dst);
        }
    };
    auto stageB = [&](int s) {
        char* base = smem + 65536 + (s & 3) * SLABB;
#pragma unroll
        for (int h = 0; h < 2; ++h) {
            int p  = h * 512 + tid;
            int rp = p >> 3;
            int j  = (p & 7) ^ (rp & 7);
            const unsigned short* src =
                Bt + (size_t)(bcol + 2 * rp + (j >> 2)) * K + s * KS + (j & 3) * 8;
            void* dst = base + (h * 512 + wave * 64) * 16;
            load_lds16(src, dst);
        }
    };

    f32x4 acc[8][4] = {};

    // prologue: stage slabs 0,1,2 (12 loads/thread in flight)
    stageA(0); stageB(0);
    stageA(1); stageB(1);
    stageA(2); stageB(2);

    const int kb  = (lane >> 4) * 16;  // byte offset of this lane's k-chunk
    const int l15 = lane & 15;

    // steady state: at loop top, slabs s,s+1,s+2 outstanding (12 loads);
    // vmcnt(8) completes slab s's 4.
    for (int s = 0; s < NSLAB - 2; ++s) {
        KSTEP(s, "vmcnt(8)", (s + 3 < NSLAB));
    }
    // tail: 8 then 4 loads outstanding — drain 4 -> 0.
    KSTEP(NSLAB - 2, "vmcnt(4)", false);
    KSTEP(NSLAB - 1, "vmcnt(0)", false);

    // ---------------- epilogue ----------------
    const float s_w = s_w_p[0];
    const float s_b = s_b_p[0];
    const int   z_b = z_b_p[0];
    const int row0 = brow + wr * 128;
    const int col0 = bcol + wc * 64;
#pragma unroll
    for (int n = 0; n < 4; ++n) {
        int col = col0 + n * 16 + l15;
        float bias = s_b * (float)(bias_q[col] - z_b);
#pragma unroll
        for (int m = 0; m < 8; ++m) {
#pragma unroll
            for (int r = 0; r < 4; ++r) {
                int row = row0 + m * 16 + (lane >> 4) * 4 + r;
                float v = acc[m][n][r] * s_w + bias;
                if (EPI == 0) {
                    float ge = 0.5f * v * (1.0f + erff(v * 0.70710678118654752f));
                    ((unsigned short*)Cout)[(size_t)row * N + col] = f2bf(ge);
                } else {
                    ((float*)Cout)[(size_t)row * N + col] = v;
                }
            }
        }
    }
}

extern "C" void kernel_launch(void* const* d_in, const int* in_sizes, int n_in,
                              void* d_out, int out_size, void* d_ws, size_t ws_size,
                              hipStream_t stream) {
    const float* x        = (const float*)d_in[0];
    const int*   w_fc_q   = (const int*)d_in[1];
    const int*   b_fc_q   = (const int*)d_in[2];
    const int*   w_proj_q = (const int*)d_in[3];
    const int*   b_proj_q = (const int*)d_in[4];
    const float* s_fc_w   = (const float*)d_in[5];
    const float* s_fc_b   = (const float*)d_in[6];
    const float* s_proj_w = (const float*)d_in[7];
    const float* s_proj_b = (const float*)d_in[8];
    const int*   z_fc_w   = (const int*)d_in[9];
    const int*   z_fc_b   = (const int*)d_in[10];
    const int*   z_proj_w = (const int*)d_in[11];
    const int*   z_proj_b = (const int*)d_in[12];

    const int M = 4 * 2048;
    const int E = 2048;
    const int H = 4 * 2048;

    size_t need = ((size_t)M * E + (size_t)H * E + (size_t)E * H + (size_t)M * H) * 2;
    if (ws_size < need) return;

    unsigned short* xb    = (unsigned short*)d_ws;
    unsigned short* wfc   = xb + (size_t)M * E;
    unsigned short* wproj = wfc + (size_t)H * E;
    unsigned short* hb    = wproj + (size_t)E * H;

    // allow 128 KiB dynamic LDS (idempotent host-side call; graph-capture safe)
    hipFuncSetAttribute(reinterpret_cast<const void*>(gemm8<0>),
                        hipFuncAttributeMaxDynamicSharedMemorySize, 131072);
    hipFuncSetAttribute(reinterpret_cast<const void*>(gemm8<1>),
                        hipFuncAttributeMaxDynamicSharedMemorySize, 131072);

    cvt_f32_to_bf16_k<<<2048, 256, 0, stream>>>(x, xb, M * E);
    cvt_i32_to_bf16_k<<<2048, 256, 0, stream>>>(w_fc_q, wfc, H * E, z_fc_w);
    cvt_i32_to_bf16_k<<<2048, 256, 0, stream>>>(w_proj_q, wproj, E * H, z_proj_w);

    // GEMM1: h[M,H] = xb * wfc^T ; scale+bias+exact GELU -> bf16
    gemm8<0><<<dim3((M / BM) * (H / BN)), 512, 131072, stream>>>(
        xb, wfc, hb, b_fc_q, s_fc_w, s_fc_b, z_fc_b, M, H, E);

    // GEMM2: out[M,E] = hb * wproj^T ; scale+bias -> f32
    gemm8<1><<<dim3((M / BM) * (E / BN)), 512, 131072, stream>>>(
        hb, wproj, (float*)d_out, b_proj_q, s_proj_w, s_proj_b, z_proj_b, M, E, H);
}

// Round 5
// 554.279 us; speedup vs baseline: 1.3293x; 1.0607x over previous
//
#include <hip/hip_runtime.h>
#include <hip/hip_bf16.h>

typedef float f32x4 __attribute__((ext_vector_type(4)));
typedef __bf16 bf16x8 __attribute__((ext_vector_type(8)));

#define BM 256
#define BN 256
#define KS 32        // slab K-width
#define SLABA 16384  // bytes per A slab (256 rows x 32 k x 2B)
#define SLABB 16384

// round-to-nearest-even fp32 -> bf16 (finite inputs only)
__device__ __forceinline__ unsigned short f2bf(float f) {
    unsigned int u = __float_as_uint(f);
    u += 0x7fffu + ((u >> 16) & 1u);
    return (unsigned short)(u >> 16);
}

__device__ __forceinline__ void load_lds16(const unsigned short* g, void* l) {
    __builtin_amdgcn_global_load_lds((const __attribute__((address_space(1))) void*)g,
                                     (__attribute__((address_space(3))) void*)l,
                                     16, 0, 0);
}

// ---------------- conversion kernels ----------------
__global__ void cvt_f32_to_bf16_k(const float* __restrict__ in,
                                  unsigned short* __restrict__ out, int n) {
    int stride = gridDim.x * blockDim.x;
    for (int i = blockIdx.x * blockDim.x + threadIdx.x; i * 4 < n; i += stride) {
        float4 v = *reinterpret_cast<const float4*>(in + (size_t)i * 4);
        ushort4 o = make_ushort4(f2bf(v.x), f2bf(v.y), f2bf(v.z), f2bf(v.w));
        *reinterpret_cast<ushort4*>(out + (size_t)i * 4) = o;
    }
}

__global__ void cvt_i32_to_bf16_k(const int* __restrict__ in,
                                  unsigned short* __restrict__ out, int n,
                                  const int* __restrict__ zp) {
    int z = zp[0];
    int stride = gridDim.x * blockDim.x;
    for (int i = blockIdx.x * blockDim.x + threadIdx.x; i * 4 < n; i += stride) {
        int4 v = *reinterpret_cast<const int4*>(in + (size_t)i * 4);
        ushort4 o = make_ushort4(f2bf((float)(v.x - z)), f2bf((float)(v.y - z)),
                                 f2bf((float)(v.z - z)), f2bf((float)(v.w - z)));
        *reinterpret_cast<ushort4*>(out + (size_t)i * 4) = o;
    }
}

// ---------------- 256x256 deep-pipelined GEMM body -------------------------
// (same verified schedule as rounds 3-4; see comments there.)

#define KSTEP(SS, VMSTR, DO_STAGE)                                             \
  {                                                                            \
    asm volatile("s_waitcnt " VMSTR ::: "memory");                             \
    __builtin_amdgcn_s_barrier();                                              \
    const int s_ = (SS);                                                       \
    const char* As = smem + (s_ & 3) * SLABA;                                  \
    const char* Bs = smem + 65536 + (s_ & 3) * SLABB;                          \
    bf16x8 a[4], b[4];                                                         \
    _Pragma("unroll") for (int m = 0; m < 4; ++m) {                            \
      int g = wr * 128 + m * 16 + l15;                                         \
      int rp = g >> 1;                                                         \
      int inner = ((g & 1) << 6) | kb;                                         \
      int off = rp * 128 + ((((inner >> 4) ^ rp) & 7) << 4);                   \
      a[m] = *reinterpret_cast<const bf16x8*>(As + off);                       \
    }                                                                          \
    _Pragma("unroll") for (int n = 0; n < 4; ++n) {                            \
      int g = wc * 64 + n * 16 + l15;                                          \
      int rp = g >> 1;                                                         \
      int inner = ((g & 1) << 6) | kb;                                         \
      int off = rp * 128 + ((((inner >> 4) ^ rp) & 7) << 4);                   \
      b[n] = *reinterpret_cast<const bf16x8*>(Bs + off);                       \
    }                                                                          \
    if (DO_STAGE) stageA(s_ + 3);                                              \
    __builtin_amdgcn_s_barrier();                                              \
    __builtin_amdgcn_s_setprio(1);                                             \
    _Pragma("unroll") for (int m = 0; m < 4; ++m)                              \
      _Pragma("unroll") for (int n = 0; n < 4; ++n)                            \
        acc[m][n] = __builtin_amdgcn_mfma_f32_16x16x32_bf16(a[m], b[n],        \
                                                            acc[m][n], 0, 0, 0); \
    __builtin_amdgcn_s_setprio(0);                                             \
    __builtin_amdgcn_s_barrier();                                              \
    _Pragma("unroll") for (int m = 0; m < 4; ++m) {                            \
      int g = wr * 128 + (m + 4) * 16 + l15;                                   \
      int rp = g >> 1;                                                         \
      int inner = ((g & 1) << 6) | kb;                                         \
      int off = rp * 128 + ((((inner >> 4) ^ rp) & 7) << 4);                   \
      a[m] = *reinterpret_cast<const bf16x8*>(As + off);                       \
    }                                                                          \
    if (DO_STAGE) stageB(s_ + 3);                                              \
    __builtin_amdgcn_s_barrier();                                              \
    __builtin_amdgcn_s_setprio(1);                                             \
    _Pragma("unroll") for (int m = 0; m < 4; ++m)                              \
      _Pragma("unroll") for (int n = 0; n < 4; ++n)                            \
        acc[m + 4][n] = __builtin_amdgcn_mfma_f32_16x16x32_bf16(a[m], b[n],    \
                                                         acc[m + 4][n], 0, 0, 0); \
    __builtin_amdgcn_s_setprio(0);                                             \
  }

template <int EPI>
__device__ __forceinline__ void gemm_body(
    char* smem,
    const unsigned short* __restrict__ A,
    const unsigned short* __restrict__ Bt,
    void* __restrict__ Cout,
    const int* __restrict__ bias_q,
    const float* __restrict__ s_w_p,
    const float* __restrict__ s_b_p,
    const int* __restrict__ z_b_p,
    int M, int N, int K)
{
    const int tid  = threadIdx.x;
    const int wave = tid >> 6;
    const int lane = tid & 63;
    const int wr = wave >> 2;        // 0..1 : row half
    const int wc = wave & 3;         // 0..3 : col quarter

    // Block map: each round = 256 blocks covering 32 row-panels x 8 col-panels;
    // XCD x owns a 4-row x 8-col rectangle -> staging window L2-resident.
    const int bid  = blockIdx.x;
    const int x8   = bid & 7;          // XCD
    const int j32  = (bid >> 3) & 31;  // block within XCD-round
    const int rnd  = bid >> 8;         // column-octet round
    const int brow = (4 * x8 + (j32 >> 3)) * BM;
    const int bcol = (rnd * 8 + (j32 & 7)) * BN;

    const int NSLAB = K / KS;

    auto stageA = [&](int s) {
        char* base = smem + (s & 3) * SLABA;
#pragma unroll
        for (int h = 0; h < 2; ++h) {
            int p  = h * 512 + tid;
            int rp = p >> 3;
            int j  = (p & 7) ^ (rp & 7);
            const unsigned short* src =
                A + (size_t)(brow + 2 * rp + (j >> 2)) * K + s * KS + (j & 3) * 8;
            void* dst = base + (h * 512 + wave * 64) * 16;  // wave-uniform; HW adds lane*16
            load_lds16(src, dst);
        }
    };
    auto stageB = [&](int s) {
        char* base = smem + 65536 + (s & 3) * SLABB;
#pragma unroll
        for (int h = 0; h < 2; ++h) {
            int p  = h * 512 + tid;
            int rp = p >> 3;
            int j  = (p & 7) ^ (rp & 7);
            const unsigned short* src =
                Bt + (size_t)(bcol + 2 * rp + (j >> 2)) * K + s * KS + (j & 3) * 8;
            void* dst = base + (h * 512 + wave * 64) * 16;
            load_lds16(src, dst);
        }
    };

    f32x4 acc[8][4] = {};

    stageA(0); stageB(0);
    stageA(1); stageB(1);
    stageA(2); stageB(2);

    const int kb  = (lane >> 4) * 16;
    const int l15 = lane & 15;

    for (int s = 0; s < NSLAB - 2; ++s) {
        KSTEP(s, "vmcnt(8)", (s + 3 < NSLAB));
    }
    KSTEP(NSLAB - 2, "vmcnt(4)", false);
    KSTEP(NSLAB - 1, "vmcnt(0)", false);

    // ---------------- epilogue ----------------
    const float s_w = s_w_p[0];
    const float s_b = s_b_p[0];
    const int   z_b = z_b_p[0];

    if (EPI == 0) {
        // h = gelu(v) -> bf16, staged through LDS (ring is dead now) for
        // coalesced dwordx4 global writes. XOR-swizzle 16B chunks vs row.
        __syncthreads();   // all waves done reading the ring
        unsigned short* hl = (unsigned short*)smem;   // 256 x 256 bf16 tile
#pragma unroll
        for (int n = 0; n < 4; ++n) {
            int col_local = wc * 64 + n * 16 + l15;
            float bias = s_b * (float)(bias_q[bcol + col_local] - z_b);
            int c16 = col_local >> 3;
            int cb  = col_local & 7;
#pragma unroll
            for (int m = 0; m < 8; ++m) {
#pragma unroll
                for (int r = 0; r < 4; ++r) {
                    int row_local = wr * 128 + m * 16 + (lane >> 4) * 4 + r;
                    float v = acc[m][n][r] * s_w + bias;
                    // tanh-GELU: v * sigmoid(1.5957691 v + 0.0713548 v^3)
                    float t2 = v * (1.5957691f + 0.0713548162f * v * v);
                    float g  = v / (1.0f + __expf(-t2));
                    int sw = c16 ^ (row_local & 31);
                    hl[row_local * 256 + sw * 8 + cb] = f2bf(g);
                }
            }
        }
        __syncthreads();
        unsigned short* C = (unsigned short*)Cout;
#pragma unroll
        for (int it = 0; it < 16; ++it) {
            int lin = it * 512 + tid;      // 16B-chunk index, 0..8191
            int rl  = lin >> 5;            // 32 chunks per row
            int c16 = lin & 31;
            int sw  = c16 ^ (rl & 31);
            uint4 d = *reinterpret_cast<const uint4*>(hl + rl * 256 + sw * 8);
            *reinterpret_cast<uint4*>(C + (size_t)(brow + rl) * N + bcol + c16 * 8) = d;
        }
    } else {
        const int row0 = brow + wr * 128;
        const int col0 = bcol + wc * 64;
#pragma unroll
        for (int n = 0; n < 4; ++n) {
            int col = col0 + n * 16 + l15;
            float bias = s_b * (float)(bias_q[col] - z_b);
#pragma unroll
            for (int m = 0; m < 8; ++m) {
#pragma unroll
                for (int r = 0; r < 4; ++r) {
                    int row = row0 + m * 16 + (lane >> 4) * 4 + r;
                    ((float*)Cout)[(size_t)row * N + col] = acc[m][n][r] * s_w + bias;
                }
            }
        }
    }
}

// Distinct symbols so rocprof rows disambiguate the two GEMMs.
__global__ __launch_bounds__(512, 2) void gemm_fc(
    const unsigned short* __restrict__ A, const unsigned short* __restrict__ Bt,
    void* __restrict__ Cout, const int* __restrict__ bias_q,
    const float* __restrict__ s_w_p, const float* __restrict__ s_b_p,
    const int* __restrict__ z_b_p, int M, int N, int K)
{
    extern __shared__ char smem[];
    gemm_body<0>(smem, A, Bt, Cout, bias_q, s_w_p, s_b_p, z_b_p, M, N, K);
}

__global__ __launch_bounds__(512, 2) void gemm_proj(
    const unsigned short* __restrict__ A, const unsigned short* __restrict__ Bt,
    void* __restrict__ Cout, const int* __restrict__ bias_q,
    const float* __restrict__ s_w_p, const float* __restrict__ s_b_p,
    const int* __restrict__ z_b_p, int M, int N, int K)
{
    extern __shared__ char smem[];
    gemm_body<1>(smem, A, Bt, Cout, bias_q, s_w_p, s_b_p, z_b_p, M, N, K);
}

extern "C" void kernel_launch(void* const* d_in, const int* in_sizes, int n_in,
                              void* d_out, int out_size, void* d_ws, size_t ws_size,
                              hipStream_t stream) {
    const float* x        = (const float*)d_in[0];
    const int*   w_fc_q   = (const int*)d_in[1];
    const int*   b_fc_q   = (const int*)d_in[2];
    const int*   w_proj_q = (const int*)d_in[3];
    const int*   b_proj_q = (const int*)d_in[4];
    const float* s_fc_w   = (const float*)d_in[5];
    const float* s_fc_b   = (const float*)d_in[6];
    const float* s_proj_w = (const float*)d_in[7];
    const float* s_proj_b = (const float*)d_in[8];
    const int*   z_fc_w   = (const int*)d_in[9];
    const int*   z_fc_b   = (const int*)d_in[10];
    const int*   z_proj_w = (const int*)d_in[11];
    const int*   z_proj_b = (const int*)d_in[12];

    const int M = 4 * 2048;
    const int E = 2048;
    const int H = 4 * 2048;

    size_t need = ((size_t)M * E + (size_t)H * E + (size_t)E * H + (size_t)M * H) * 2;
    if (ws_size < need) return;

    unsigned short* xb    = (unsigned short*)d_ws;
    unsigned short* wfc   = xb + (size_t)M * E;
    unsigned short* wproj = wfc + (size_t)H * E;
    unsigned short* hb    = wproj + (size_t)E * H;

    hipFuncSetAttribute(reinterpret_cast<const void*>(gemm_fc),
                        hipFuncAttributeMaxDynamicSharedMemorySize, 131072);
    hipFuncSetAttribute(reinterpret_cast<const void*>(gemm_proj),
                        hipFuncAttributeMaxDynamicSharedMemorySize, 131072);

    cvt_f32_to_bf16_k<<<2048, 256, 0, stream>>>(x, xb, M * E);
    cvt_i32_to_bf16_k<<<2048, 256, 0, stream>>>(w_fc_q, wfc, H * E, z_fc_w);
    cvt_i32_to_bf16_k<<<2048, 256, 0, stream>>>(w_proj_q, wproj, E * H, z_proj_w);

    // GEMM1: h[M,H] = xb * wfc^T ; scale+bias+fast GELU -> bf16
    gemm_fc<<<dim3((M / BM) * (H / BN)), 512, 131072, stream>>>(
        xb, wfc, hb, b_fc_q, s_fc_w, s_fc_b, z_fc_b, M, H, E);

    // GEMM2: out[M,E] = hb * wproj^T ; scale+bias -> f32
    gemm_proj<<<dim3((M / BM) * (E / BN)), 512, 131072, stream>>>(
        hb, wproj, (float*)d_out, b_proj_q, s_proj_w, s_proj_b, z_proj_b, M, E, H);
}